// Round 10
// baseline (935.933 us; speedup 1.0000x reference)
//
#include <hip/hip_runtime.h>
#include <hip/hip_bf16.h>
#include <stdint.h>

typedef __attribute__((ext_vector_type(4))) int i32x4;

#define M_DIM 8192
#define K_DIM 4096
#define N_DIM 16384
#define NELEM_W ((long)N_DIM * (long)K_DIM) /* 67108864 */
#define NELEM_X ((long)M_DIM * (long)K_DIM) /* 33554432 */

// ---------------- helpers ----------------

__device__ __forceinline__ void g2l16(const void* g, void* l) {
  __builtin_amdgcn_global_load_lds(
      (const __attribute__((address_space(1))) unsigned int*)g,
      (__attribute__((address_space(3))) unsigned int*)l, 16, 0, 0);
}

// ---------------- scale = max(mean(|W|), 1e-8), deterministic fp64 ----------------

__global__ void reduce_absw(const float4* __restrict__ w4, double* __restrict__ partials, int n4) {
  const int tid = threadIdx.x;
  double s = 0.0;
  const int stride = gridDim.x * blockDim.x;
  for (int i = blockIdx.x * blockDim.x + tid; i < n4; i += stride) {
    float4 v = w4[i];
    s += (double)fabsf(v.x);
    s += (double)fabsf(v.y);
    s += (double)fabsf(v.z);
    s += (double)fabsf(v.w);
  }
  __shared__ double sd[256];
  sd[tid] = s;
  __syncthreads();
  for (int off = 128; off > 0; off >>= 1) {
    if (tid < off) sd[tid] += sd[tid + off];
    __syncthreads();
  }
  if (tid == 0) partials[blockIdx.x] = sd[0];
}

__global__ void finalize_scale(const double* __restrict__ partials, float* __restrict__ sp) {
  const int tid = threadIdx.x;
  double s = 0.0;
#pragma unroll
  for (int j = 0; j < 8; ++j) s += partials[tid * 8 + j];
  __shared__ double sd[256];
  sd[tid] = s;
  __syncthreads();
  for (int off = 128; off > 0; off >>= 1) {
    if (tid < off) sd[tid] += sd[tid + off];
    __syncthreads();
  }
  if (tid == 0) {
    double mean = sd[0] / (double)NELEM_W;
    float sc = (float)mean;
    if (sc < 1e-8f) sc = 1e-8f;
    sp[0] = sc;
  }
}

// ---------------- quantize W -> ternary 2-bit packed ----------------
// Code c = round(clip(w/s)) + 1 in {0,1,2}. One thread packs 16 contiguous k
// into one dword. Packed global layout (mirrors the LDS tile image):
//   row n (1024B): [kt 0..31][32B tile-slice], slice: slot s (8B) x {ks0 4B, ks1 4B};
//   (kq,ks) -> slot s = (kq + (n>>2)) & 3  (bank-decorrelating rotation, baked here).
// k for a dword: k = kt*128 + ks*64 + kq*16 + i (i = bit-pair index 0..15).

__global__ __launch_bounds__(256)
void quant_w_pack(const float* __restrict__ w, unsigned int* __restrict__ q,
                  const float* __restrict__ sp) {
  const float sc = sp[0];
  const int idx = blockIdx.x * 256 + threadIdx.x;   // total N_DIM*256 = 4.19M
  const int n = idx >> 8;
  const int r = idx & 255;
  const int kt = r >> 3;
  const int kq = (r >> 1) & 3;
  const int ks = r & 1;
  const int k0 = kt * 128 + ks * 64 + kq * 16;
  const float4* src = (const float4*)(w + (long)n * K_DIM + k0);
  unsigned int d = 0;
#pragma unroll
  for (int j = 0; j < 4; ++j) {
    float4 v = src[j];
    int c0 = (int)rintf(fminf(fmaxf(v.x / sc, -1.f), 1.f)) + 1;
    int c1 = (int)rintf(fminf(fmaxf(v.y / sc, -1.f), 1.f)) + 1;
    int c2 = (int)rintf(fminf(fmaxf(v.z / sc, -1.f), 1.f)) + 1;
    int c3 = (int)rintf(fminf(fmaxf(v.w / sc, -1.f), 1.f)) + 1;
    d |= ((unsigned)c0 << (2 * (j * 4 + 0))) | ((unsigned)c1 << (2 * (j * 4 + 1)))
       | ((unsigned)c2 << (2 * (j * 4 + 2))) | ((unsigned)c3 << (2 * (j * 4 + 3)));
  }
  const int sl = (kq + (n >> 2)) & 3;
  q[(n * 1024 + kt * 32 + sl * 8 + ks * 4) >> 2] = d;
}

// ---------------- quantize x rows -> int8 with per-row scale ----------------

__global__ __launch_bounds__(256)
void quant_x_i8(const float* __restrict__ x, char* __restrict__ xq,
                float* __restrict__ s_row) {
  const int row = blockIdx.x;
  const int tid = threadIdx.x;
  const float4* xr = (const float4*)(x + (long)row * K_DIM);
  float4 v[4];
  float m = 0.f;
#pragma unroll
  for (int k = 0; k < 4; ++k) {
    v[k] = xr[tid + 256 * k];
    m = fmaxf(m, fmaxf(fmaxf(fabsf(v[k].x), fabsf(v[k].y)),
                       fmaxf(fabsf(v[k].z), fabsf(v[k].w))));
  }
  __shared__ float red[256];
  red[tid] = m;
  __syncthreads();
  for (int off = 128; off > 0; off >>= 1) {
    if (tid < off) red[tid] = fmaxf(red[tid], red[tid + off]);
    __syncthreads();
  }
  const float mx = red[0];
  const float inv = (mx > 0.f) ? (127.f / mx) : 0.f;
  if (tid == 0) s_row[row] = (mx > 0.f) ? (mx / 127.f) : 0.f;
  char4* out = (char4*)(xq + (long)row * K_DIM);
#pragma unroll
  for (int k = 0; k < 4; ++k) {
    char4 o;
    o.x = (char)fminf(fmaxf(rintf(v[k].x * inv), -127.f), 127.f);
    o.y = (char)fminf(fmaxf(rintf(v[k].y * inv), -127.f), 127.f);
    o.z = (char)fminf(fmaxf(rintf(v[k].z * inv), -127.f), 127.f);
    o.w = (char)fminf(fmaxf(rintf(v[k].w * inv), -127.f), 127.f);
    out[tid + 256 * k] = o;
  }
}

// ---------------- 256x256 i8 GEMM, packed-2bit B, one barrier per K-tile ----------------
// Identical to r9 except unpk_dword: the r9 spread (x*0x41041)&0x03030303 was NOT
// carry-free (c3+c0 add at bits 6-7; c0=c3=2 carries into byte1's selector ->
// ~2.4% of weights perturbed +-s -> absmax 53). Fixed carry-free form:
//   sel = ((x & 0x3F) * 0x41041) & 0x00030303   // f0,f1,f2: shifted copies occupy
//                                               // DISJOINT 6-bit windows (0-5,6-11,
//                                               // 12-17,18-23) -> pure concatenation
//   sel |= (x >> 6) << 24;                      // f3 direct to byte 3
// Sync structure = r8 skeleton (HW-proven): stage t+1 -> buf^1 at tile start,
// vmcnt(0)+s_barrier at tile end; staging never touches the buffer being read.

#define FENCE asm volatile("" ::: "memory")
#define BAR do { FENCE; __builtin_amdgcn_s_barrier(); FENCE; } while (0)
#define VMW0 asm volatile("s_waitcnt vmcnt(0)" ::: "memory")
#define PRIO1 __builtin_amdgcn_s_setprio(1)
#define PRIO0 __builtin_amdgcn_s_setprio(0)

__device__ __forceinline__ int unpk_dword(unsigned int v, int q, unsigned int lut) {
  unsigned int x = (v >> (8 * q)) & 0xFFu;
  unsigned int sel = ((x & 0x3Fu) * 0x41041u) & 0x00030303u;  // carry-free: disjoint windows
  sel |= (x >> 6) << 24;                                      // f3 -> byte 3
  int out;
  asm("v_perm_b32 %0, %1, %2, %3" : "=v"(out) : "v"(lut), "v"(lut), "v"(sel));
  return out;
}

__device__ __forceinline__ i32x4 unpk_op(unsigned int v, unsigned int lut) {
  i32x4 r;
  r[0] = unpk_dword(v, 0, lut);
  r[1] = unpk_dword(v, 1, lut);
  r[2] = unpk_dword(v, 2, lut);
  r[3] = unpk_dword(v, 3, lut);
  return r;
}

// stage A half-tile h (128 rows) into buffer ob at K-tile kt (2 x 16B loads)
#define STG_A(ob, h, kt) do { \
    const char* g_ = Ac + aG + (unsigned)(h) * 524288u + (unsigned)(kt) * 128u; \
    char* l_ = lds + (unsigned)(ob) * 32768u + (unsigned)(h) * 16384u + ldsT; \
    g2l16(g_, l_); g2l16(g_ + 262144u, l_ + 8192u); \
  } while (0)
// stage packed B tile (8KB) into buffer ob (1 x 16B load)
#define STG_B(ob, kt) do { \
    const char* g_ = Bc + bGp + (unsigned)(kt) * 32u; \
    char* l_ = lds + 65536u + (unsigned)(ob) * 8192u + ldsT; \
    g2l16(g_, l_); \
  } while (0)

// read A m-tile mt (16 rows) into a[mt*2 .. mt*2+1]
#define RD_A(bb, mt) do { \
    a[(mt) * 2 + 0] = *(const i32x4*)(lds + aR##bb + (unsigned)(mt) * 2048u + coff0); \
    a[(mt) * 2 + 1] = *(const i32x4*)(lds + aR##bb + (unsigned)(mt) * 2048u + coff1); \
  } while (0)
// read packed B nt-pair pp into pk{par} (2 x ds_read_b64)
#define RD_B64(par, bb, pp) do { \
    pk##par[0] = *(const uint2*)(lds + bR##bb + (unsigned)(pp) * 1024u); \
    pk##par[1] = *(const uint2*)(lds + bR##bb + (unsigned)(pp) * 1024u + 512u); \
  } while (0)
#define UNPK(par) do { \
    bu##par[0] = unpk_op(pk##par[0].x, lut); bu##par[1] = unpk_op(pk##par[0].y, lut); \
    bu##par[2] = unpk_op(pk##par[1].x, lut); bu##par[3] = unpk_op(pk##par[1].y, lut); \
  } while (0)

#define MFMA8(NP, MH, BU) do { PRIO1; \
    _Pragma("unroll") \
    for (int dm = 0; dm < 2; ++dm) \
      _Pragma("unroll") \
      for (int dn = 0; dn < 2; ++dn) \
        _Pragma("unroll") \
        for (int ks = 0; ks < 2; ++ks) \
          acc[(MH) * 2 + dm][(NP) * 2 + dn] = __builtin_amdgcn_mfma_i32_16x16x64_i8( \
              a[((MH) * 2 + dm) * 2 + ks], BU[dn * 2 + ks], acc[(MH) * 2 + dm][(NP) * 2 + dn], 0, 0, 0); \
    PRIO0; } while (0)

// one K-tile: read buf bb, stage kt1 -> buf ob (if DO_STG); reads prefetched 1-2
// sub-phases ahead; pk/bu ping-pong by nt-pair parity.
#define TILE(bb, ob, kt1, DO_STG) do { \
    if (DO_STG) { STG_A(ob, 0, kt1); STG_A(ob, 1, kt1); STG_B(ob, kt1); } \
    RD_B64(0, bb, 0); \
    RD_A(bb, 0); RD_A(bb, 1); \
    UNPK(0); \
    RD_B64(1, bb, 1); \
    RD_A(bb, 2); RD_A(bb, 3); \
    MFMA8(0, 0, bu0); \
    UNPK(1); \
    MFMA8(0, 1, bu0); \
    RD_B64(0, bb, 2); \
    MFMA8(1, 0, bu1); \
    UNPK(0); \
    MFMA8(1, 1, bu1); \
    RD_B64(1, bb, 3); \
    MFMA8(2, 0, bu0); \
    UNPK(1); \
    MFMA8(2, 1, bu0); \
    MFMA8(3, 0, bu1); \
    MFMA8(3, 1, bu1); \
  } while (0)

__global__ __launch_bounds__(512, 2)
void gemm_i8(const char* __restrict__ A, const char* __restrict__ B,
             float* __restrict__ C, const float* __restrict__ sp,
             const float* __restrict__ s_row) {
  extern __shared__ char lds[];

  const int tid = threadIdx.x;
  const int wave = tid >> 6, lane = tid & 63;
  const int fr = lane & 15, fq = lane >> 4;
  const int wm = wave >> 1;        // 0..3 (M band of 64 rows)
  const int wn = wave & 1;         // 0..1 (N band of 128 cols)

  // bijective XCD swizzle (2048 % 8 == 0)
  int wgid = blockIdx.x;
  wgid = (wgid & 7) * ((int)gridDim.x >> 3) + (wgid >> 3);
  const int bm = wgid >> 6;
  const int bn = wgid & 63;

  // A staging addressing (identical to r5)
  const int r0 = tid >> 3;
  const int pslot = tid & 7;
  const int lslot = pslot ^ (r0 & 7);
  const unsigned aG = (unsigned)(bm * 256 + r0) * (unsigned)K_DIM + (unsigned)lslot * 16u;
  // B staging: packed rows 1024B; tile slice 32B; thread -> (row tid>>1, half tid&1)
  const unsigned bGp = (unsigned)(bn * 256 + (tid >> 1)) * 1024u + (unsigned)(tid & 1) * 16u;
  const unsigned ldsT = (unsigned)tid * 16u;
  const char* Ac = A;
  const char* Bc = B;

  // A fragment read addressing (identical to r5): rows 128B, phys slot = logical ^ (row&7)
  const unsigned axor = (unsigned)(fr & 7) << 4;
  const unsigned coff0 = ((unsigned)(fq * 16)) ^ axor;
  const unsigned coff1 = ((unsigned)(64 + fq * 16)) ^ axor;
  const unsigned aR0 = (unsigned)((wm >> 1) * 16384 + (wm & 1) * 8192 + fr * 128);
  const unsigned aR1 = aR0 + 32768u;
  // B packed read addressing: row = wn*128 + nt*16 + fr, rows 32B,
  // slot = (kq + (row>>2)) & 3 with kq = lane>>4; nt*16 contributes 0 mod 4.
  const unsigned bslot = (unsigned)(((lane >> 4) + (fr >> 2)) & 3);
  const unsigned bR0 = 65536u + (unsigned)(wn * 128 + fr) * 32u + bslot * 8u;
  const unsigned bR1 = bR0 + 8192u;

  const unsigned int lut = 0x000100FFu;  // code 0->-1, 1->0, 2->+1

  i32x4 acc[4][8] = {};
  i32x4 a[8];
  uint2 pk0[2], pk1[2];
  i32x4 bu0[4], bu1[4];

  // prologue: stage tile0 -> buf0 (5 loads); drain; join
  STG_A(0, 0, 0); STG_A(0, 1, 0); STG_B(0, 0);
  VMW0;
  BAR;

#pragma unroll 1
  for (int i = 0; i < 15; ++i) {
    TILE(0, 1, 2 * i + 1, true);
    VMW0; BAR;
    TILE(1, 0, 2 * i + 2, true);
    VMW0; BAR;
  }
  TILE(0, 1, 31, true);
  VMW0; BAR;
  TILE(1, 0, 0, false);

  // epilogue: C/D 16x16 layout col = fr, row = fq*4 + j
  const float sw = sp[0];
  const int crow0 = bm * 256 + wm * 64 + fq * 4;
  const int ccol0 = bn * 256 + wn * 128 + fr;
#pragma unroll
  for (int mt = 0; mt < 4; ++mt) {
#pragma unroll
    for (int j = 0; j < 4; ++j) {
      const int row = crow0 + mt * 16 + j;
      const float scl = s_row[row] * sw;
#pragma unroll
      for (int nt = 0; nt < 8; ++nt) {
        C[(long)row * N_DIM + (ccol0 + nt * 16)] = (float)acc[mt][nt][j] * scl;
      }
    }
  }
}

// ---------------- fallback (ws too small): bf16 on-the-fly 128^2 ----------------

typedef __hip_bfloat16 bf16;
typedef __attribute__((ext_vector_type(8))) short short8;
typedef __attribute__((ext_vector_type(4))) float f32x4;

__device__ __forceinline__ unsigned short f2bf(float f) {
  unsigned int u = __float_as_uint(f);
  u += 0x7FFFu + ((u >> 16) & 1u);
  return (unsigned short)(u >> 16);
}

__global__ __launch_bounds__(256)
void gemm_fly(const float* __restrict__ X, const float* __restrict__ W,
              float* __restrict__ C, const float* __restrict__ sp) {
  __shared__ alignas(16) bf16 As[128 * 32];
  __shared__ alignas(16) bf16 Bs[128 * 32];

  const int tid = threadIdx.x;
  const int wave = tid >> 6;
  const int lane = tid & 63;

  int wgid = blockIdx.x;
  wgid = (wgid & 7) * ((int)gridDim.x >> 3) + (wgid >> 3);
  const int nbn = N_DIM / 128;
  const int bm = wgid / nbn;
  const int bn = wgid % nbn;

  const float sc = sp[0];

  const int wr = (wave >> 1) * 64;
  const int wc = (wave & 1) * 64;
  const int fr = lane & 15;
  const int fq = lane >> 4;
  const char* AsB = (const char*)As;
  const char* BsB = (const char*)Bs;
  const unsigned aoff = (unsigned)((wr + fr) * 64 + fq * 16);
  const unsigned boff = (unsigned)((wc + fr) * 64 + fq * 16);

  f32x4 acc[4][4] = {};

  for (int kt = 0; kt < K_DIM; kt += 32) {
#pragma unroll
    for (int r = 0; r < 4; ++r) {
      int e = r * 1024 + tid * 4;
      int row = e >> 5;
      int k4 = e & 31;
      float4 xv = *(const float4*)(X + (long)(bm * 128 + row) * K_DIM + kt + k4);
      ushort4 xb;
      xb.x = f2bf(xv.x); xb.y = f2bf(xv.y); xb.z = f2bf(xv.z); xb.w = f2bf(xv.w);
      *(ushort4*)(As + e) = xb;
      float4 wv = *(const float4*)(W + (long)(bn * 128 + row) * K_DIM + kt + k4);
      ushort4 wb;
      wb.x = f2bf(rintf(fminf(fmaxf(wv.x / sc, -1.f), 1.f)));
      wb.y = f2bf(rintf(fminf(fmaxf(wv.y / sc, -1.f), 1.f)));
      wb.z = f2bf(rintf(fminf(fmaxf(wv.z / sc, -1.f), 1.f)));
      wb.w = f2bf(rintf(fminf(fmaxf(wv.w / sc, -1.f), 1.f)));
      *(ushort4*)(Bs + e) = wb;
    }
    __syncthreads();

    short8 a[4], b[4];
#pragma unroll
    for (int m = 0; m < 4; ++m)
      a[m] = *(const short8*)(AsB + aoff + m * (16 * 64));
#pragma unroll
    for (int n = 0; n < 4; ++n)
      b[n] = *(const short8*)(BsB + boff + n * (16 * 64));
#pragma unroll
    for (int m = 0; m < 4; ++m)
#pragma unroll
      for (int n = 0; n < 4; ++n)
        acc[m][n] = __builtin_amdgcn_mfma_f32_16x16x32_bf16(a[m], b[n], acc[m][n], 0, 0, 0);

    __syncthreads();
  }

  const long crow0 = (long)(bm * 128 + wr + fq * 4);
  const int ccol0 = bn * 128 + wc + fr;
#pragma unroll
  for (int m = 0; m < 4; ++m)
#pragma unroll
    for (int n = 0; n < 4; ++n)
#pragma unroll
      for (int j = 0; j < 4; ++j) {
        long row = crow0 + (long)(m * 16 + j);
        int col = ccol0 + n * 16;
        C[row * N_DIM + col] = acc[m][n][j] * sc;
      }
}

// ---------------- launch ----------------

extern "C" void kernel_launch(void* const* d_in, const int* in_sizes, int n_in,
                              void* d_out, int out_size, void* d_ws, size_t ws_size,
                              hipStream_t stream) {
  const float* x = (const float*)d_in[0];
  const float* w = (const float*)d_in[1];
  float* out = (float*)d_out;

  char* ws = (char*)d_ws;
  double* partials = (double*)ws;                    // 16 KB
  float* sp = (float*)(ws + 16384);                  // scale (mean|W|)
  const size_t SROW_OFF = 32768;                     // 8192 floats
  const size_t WQ_OFF = SROW_OFF + 32768;            // packed W: N*1024 B = 16.8 MB
  const size_t XQ_OFF = WQ_OFF + (size_t)N_DIM * 1024;
  const size_t NEEDED = XQ_OFF + (size_t)NELEM_X;    // ~50.4 MB

  reduce_absw<<<2048, 256, 0, stream>>>((const float4*)w, partials, (int)(NELEM_W / 4));
  finalize_scale<<<1, 256, 0, stream>>>(partials, sp);

  if (ws_size >= NEEDED) {
    float* s_row = (float*)(ws + SROW_OFF);
    unsigned int* wq = (unsigned int*)(ws + WQ_OFF);
    char* xq = ws + XQ_OFF;
    quant_w_pack<<<(N_DIM * 256) / 256, 256, 0, stream>>>(w, wq, sp);
    quant_x_i8<<<M_DIM, 256, 0, stream>>>(x, xq, s_row);

    static const int lds_bytes = 81920;
    (void)hipFuncSetAttribute((const void*)gemm_i8,
                              hipFuncAttributeMaxDynamicSharedMemorySize, lds_bytes);
    const int grid = (M_DIM / 256) * (N_DIM / 256); // 2048
    gemm_i8<<<grid, 512, lds_bytes, stream>>>(xq, (const char*)wq, out, sp, s_row);
  } else {
    const int grid = (M_DIM / 128) * (N_DIM / 128);
    gemm_fly<<<grid, 256, 0, stream>>>(x, w, out, sp);
  }
}

// Round 11
// 866.954 us; speedup vs baseline: 1.0796x; 1.0796x over previous
//
#include <hip/hip_runtime.h>
#include <hip/hip_bf16.h>
#include <stdint.h>

typedef __attribute__((ext_vector_type(4))) int i32x4;

#define M_DIM 8192
#define K_DIM 4096
#define N_DIM 16384
#define NELEM_W ((long)N_DIM * (long)K_DIM) /* 67108864 */
#define NELEM_X ((long)M_DIM * (long)K_DIM) /* 33554432 */

// ---------------- helpers ----------------

__device__ __forceinline__ void g2l16(const void* g, void* l) {
  __builtin_amdgcn_global_load_lds(
      (const __attribute__((address_space(1))) unsigned int*)g,
      (__attribute__((address_space(3))) unsigned int*)l, 16, 0, 0);
}

// ---------------- scale = max(mean(|W|), 1e-8), deterministic fp64 ----------------

__global__ void reduce_absw(const float4* __restrict__ w4, double* __restrict__ partials, int n4) {
  const int tid = threadIdx.x;
  double s = 0.0;
  const int stride = gridDim.x * blockDim.x;
  for (int i = blockIdx.x * blockDim.x + tid; i < n4; i += stride) {
    float4 v = w4[i];
    s += (double)fabsf(v.x);
    s += (double)fabsf(v.y);
    s += (double)fabsf(v.z);
    s += (double)fabsf(v.w);
  }
  __shared__ double sd[256];
  sd[tid] = s;
  __syncthreads();
  for (int off = 128; off > 0; off >>= 1) {
    if (tid < off) sd[tid] += sd[tid + off];
    __syncthreads();
  }
  if (tid == 0) partials[blockIdx.x] = sd[0];
}

__global__ void finalize_scale(const double* __restrict__ partials, float* __restrict__ sp) {
  const int tid = threadIdx.x;
  double s = 0.0;
#pragma unroll
  for (int j = 0; j < 8; ++j) s += partials[tid * 8 + j];
  __shared__ double sd[256];
  sd[tid] = s;
  __syncthreads();
  for (int off = 128; off > 0; off >>= 1) {
    if (tid < off) sd[tid] += sd[tid + off];
    __syncthreads();
  }
  if (tid == 0) {
    double mean = sd[0] / (double)NELEM_W;
    float sc = (float)mean;
    if (sc < 1e-8f) sc = 1e-8f;
    sp[0] = sc;
  }
}

// ---------------- quantize W -> ternary int8 {-1,0,+1} ----------------

__global__ void quant_w_i8(const float4* __restrict__ w4, char* __restrict__ q,
                           const float* __restrict__ sp, int n4) {
  const float sc = sp[0];
  const int stride = gridDim.x * blockDim.x;
  for (int i = blockIdx.x * blockDim.x + threadIdx.x; i < n4; i += stride) {
    float4 v = w4[i];
    char4 o;
    o.x = (char)rintf(fminf(fmaxf(v.x / sc, -1.f), 1.f));
    o.y = (char)rintf(fminf(fmaxf(v.y / sc, -1.f), 1.f));
    o.z = (char)rintf(fminf(fmaxf(v.z / sc, -1.f), 1.f));
    o.w = (char)rintf(fminf(fmaxf(v.w / sc, -1.f), 1.f));
    *(char4*)(q + (long)i * 4) = o;
  }
}

// ---------------- quantize x rows -> int8 with per-row scale ----------------

__global__ __launch_bounds__(256)
void quant_x_i8(const float* __restrict__ x, char* __restrict__ xq,
                float* __restrict__ s_row) {
  const int row = blockIdx.x;
  const int tid = threadIdx.x;
  const float4* xr = (const float4*)(x + (long)row * K_DIM);
  float4 v[4];
  float m = 0.f;
#pragma unroll
  for (int k = 0; k < 4; ++k) {
    v[k] = xr[tid + 256 * k];
    m = fmaxf(m, fmaxf(fmaxf(fabsf(v[k].x), fabsf(v[k].y)),
                       fmaxf(fabsf(v[k].z), fabsf(v[k].w))));
  }
  __shared__ float red[256];
  red[tid] = m;
  __syncthreads();
  for (int off = 128; off > 0; off >>= 1) {
    if (tid < off) red[tid] = fmaxf(red[tid], red[tid + off]);
    __syncthreads();
  }
  const float mx = red[0];
  const float inv = (mx > 0.f) ? (127.f / mx) : 0.f;
  if (tid == 0) s_row[row] = (mx > 0.f) ? (mx / 127.f) : 0.f;
  char4* out = (char4*)(xq + (long)row * K_DIM);
#pragma unroll
  for (int k = 0; k < 4; ++k) {
    char4 o;
    o.x = (char)fminf(fmaxf(rintf(v[k].x * inv), -127.f), 127.f);
    o.y = (char)fminf(fmaxf(rintf(v[k].y * inv), -127.f), 127.f);
    o.z = (char)fminf(fmaxf(rintf(v[k].z * inv), -127.f), 127.f);
    o.w = (char)fminf(fmaxf(rintf(v[k].w * inv), -127.f), 127.f);
    out[tid + 256 * k] = o;
  }
}

// ---------------- 128x256 i8 GEMM, 16x16x64 MFMA, 2 blocks/CU ----------------
// Occupancy lever vs r7 (which was 252 regs/wave -> 2 waves/SIMD, 1 block/CU,
// one barrier domain -> LDS-read bursts serialized with MFMA): per-wave acc
// halved to 64 regs (wave tile 64x64), LDS 48KB (2 dbuf x (A 8KB + B 16KB)),
// __launch_bounds__(512,4) caps VGPR at 128 -> 2 INDEPENDENT blocks/CU whose
// barriers don't align -> one block's MFMA covers the other's read bursts.
// BK=64: each fragment = 1 ds_read_b128 covering the full K-step (one MFMA).
// Swizzle: rows 64B = 4 slots of 16B; phys slot = logical ^ (row&3), baked into
// the global source (both-sides rule); read spread = 2 lanes/bank-quad (free).
// Sync = r8 skeleton (HW-proven): stage t+1 -> buf^1 at tile start (3 g2l16),
// vmcnt(0) + s_barrier at tile end; staging never touches the buffer being read.

#define FENCE asm volatile("" ::: "memory")
#define BAR do { FENCE; __builtin_amdgcn_s_barrier(); FENCE; } while (0)
#define VMW0 asm volatile("s_waitcnt vmcnt(0)" ::: "memory")
#define PRIO1 __builtin_amdgcn_s_setprio(1)
#define PRIO0 __builtin_amdgcn_s_setprio(0)

// stage A tile (8KB, 1 load/thread) and B tile (16KB, 2 loads/thread) for kt -> buf ob
#define STG(ob, kt) do { \
    g2l16(Ac + aG + (unsigned)(kt) * 64u, lds + (unsigned)(ob) * 8192u + ldsT); \
    char* bl_ = lds + 16384u + (unsigned)(ob) * 16384u + ldsT; \
    g2l16(Bc + bG + (unsigned)(kt) * 64u, bl_); \
    g2l16(Bc + bG + 524288u + (unsigned)(kt) * 64u, bl_ + 8192u); \
  } while (0)

// one K-tile: read 4 A + 4 B frags from buf bb, 16 MFMA; stage kt1 -> buf ob
#define TILE(bb, ob, kt1, DO_STG) do { \
    if (DO_STG) STG(ob, kt1); \
    _Pragma("unroll") \
    for (int mt = 0; mt < 4; ++mt) \
      a[mt] = *(const i32x4*)(lds + (unsigned)(bb) * 8192u + aRd + (unsigned)mt * 1024u); \
    _Pragma("unroll") \
    for (int nt = 0; nt < 4; ++nt) \
      b[nt] = *(const i32x4*)(lds + 16384u + (unsigned)(bb) * 16384u + bRd + (unsigned)nt * 1024u); \
    PRIO1; \
    _Pragma("unroll") \
    for (int mt = 0; mt < 4; ++mt) \
      _Pragma("unroll") \
      for (int nt = 0; nt < 4; ++nt) \
        acc[mt][nt] = __builtin_amdgcn_mfma_i32_16x16x64_i8(a[mt], b[nt], acc[mt][nt], 0, 0, 0); \
    PRIO0; \
  } while (0)

__global__ __launch_bounds__(512, 4)
void gemm_i8(const char* __restrict__ A, const char* __restrict__ B,
             float* __restrict__ C, const float* __restrict__ sp,
             const float* __restrict__ s_row) {
  extern __shared__ char lds[];

  const int tid = threadIdx.x;
  const int wave = tid >> 6, lane = tid & 63;
  const int fr = lane & 15, fq = lane >> 4;
  const int wm = wave >> 2;        // 0..1 (M band of 64 rows)
  const int wn = wave & 3;         // 0..3 (N band of 64 cols)

  // bijective XCD swizzle (4096 % 8 == 0)
  int wgid = blockIdx.x;
  wgid = (wgid & 7) * ((int)gridDim.x >> 3) + (wgid >> 3);
  const int bm = wgid >> 6;        // 64 M-tiles of 128
  const int bn = wgid & 63;        // 64 N-tiles of 256

  // staging: thread -> (row r0 = tid>>2, phys slot tid&3); logical = phys ^ (row&3)
  const int r0 = tid >> 2;
  const int lslot = (tid & 3) ^ (r0 & 3);
  const unsigned aG = (unsigned)(bm * 128 + r0) * (unsigned)K_DIM + (unsigned)lslot * 16u;
  const unsigned bG = (unsigned)(bn * 256 + r0) * (unsigned)K_DIM + (unsigned)lslot * 16u;
  const unsigned ldsT = (unsigned)tid * 16u;
  const char* Ac = A;
  const char* Bc = B;

  // fragment reads: rows 64B; byte = row*64 + (fq ^ (row&3))*16; row&3 == fr&3
  const unsigned sswz = ((unsigned)(fq ^ (fr & 3))) << 4;
  const unsigned aRd = (unsigned)(wm * 64 + fr) * 64u + sswz;   // + mt*1024 + bb*8192
  const unsigned bRd = (unsigned)(wn * 64 + fr) * 64u + sswz;   // + nt*1024 (+16384 + bb*16384)

  i32x4 acc[4][4] = {};
  i32x4 a[4], b[4];

  // prologue: stage tile0 -> buf0 (3 loads); drain; join
  STG(0, 0);
  VMW0;
  BAR;

#pragma unroll 1
  for (int i = 0; i < 31; ++i) {
    TILE(0, 1, 2 * i + 1, true);   // t=2i   reads buf0, stages t+1 -> buf1
    VMW0; BAR;
    TILE(1, 0, 2 * i + 2, true);   // t=2i+1 reads buf1, stages t+2 -> buf0
    VMW0; BAR;
  }
  TILE(0, 1, 63, true);            // t=62 reads buf0, stages t63 -> buf1
  VMW0; BAR;
  TILE(1, 0, 0, false);            // t=63: compute only

  // epilogue: C/D 16x16 layout col = fr, row = fq*4 + j; out = acc * s_row[row] * sw
  const float sw = sp[0];
  const int crow0 = bm * 128 + wm * 64 + fq * 4;
  const int ccol0 = bn * 256 + wn * 64 + fr;
#pragma unroll
  for (int mt = 0; mt < 4; ++mt) {
#pragma unroll
    for (int j = 0; j < 4; ++j) {
      const int row = crow0 + mt * 16 + j;
      const float scl = s_row[row] * sw;
#pragma unroll
      for (int nt = 0; nt < 4; ++nt) {
        C[(long)row * N_DIM + (ccol0 + nt * 16)] = (float)acc[mt][nt][j] * scl;
      }
    }
  }
}

// ---------------- fallback (ws too small): bf16 on-the-fly 128^2 ----------------

typedef __hip_bfloat16 bf16;
typedef __attribute__((ext_vector_type(8))) short short8;
typedef __attribute__((ext_vector_type(4))) float f32x4;

__device__ __forceinline__ unsigned short f2bf(float f) {
  unsigned int u = __float_as_uint(f);
  u += 0x7FFFu + ((u >> 16) & 1u);
  return (unsigned short)(u >> 16);
}

__global__ __launch_bounds__(256)
void gemm_fly(const float* __restrict__ X, const float* __restrict__ W,
              float* __restrict__ C, const float* __restrict__ sp) {
  __shared__ alignas(16) bf16 As[128 * 32];
  __shared__ alignas(16) bf16 Bs[128 * 32];

  const int tid = threadIdx.x;
  const int wave = tid >> 6;
  const int lane = tid & 63;

  int wgid = blockIdx.x;
  wgid = (wgid & 7) * ((int)gridDim.x >> 3) + (wgid >> 3);
  const int nbn = N_DIM / 128;
  const int bm = wgid / nbn;
  const int bn = wgid % nbn;

  const float sc = sp[0];

  const int wr = (wave >> 1) * 64;
  const int wc = (wave & 1) * 64;
  const int fr = lane & 15;
  const int fq = lane >> 4;
  const char* AsB = (const char*)As;
  const char* BsB = (const char*)Bs;
  const unsigned aoff = (unsigned)((wr + fr) * 64 + fq * 16);
  const unsigned boff = (unsigned)((wc + fr) * 64 + fq * 16);

  f32x4 acc[4][4] = {};

  for (int kt = 0; kt < K_DIM; kt += 32) {
#pragma unroll
    for (int r = 0; r < 4; ++r) {
      int e = r * 1024 + tid * 4;
      int row = e >> 5;
      int k4 = e & 31;
      float4 xv = *(const float4*)(X + (long)(bm * 128 + row) * K_DIM + kt + k4);
      ushort4 xb;
      xb.x = f2bf(xv.x); xb.y = f2bf(xv.y); xb.z = f2bf(xv.z); xb.w = f2bf(xv.w);
      *(ushort4*)(As + e) = xb;
      float4 wv = *(const float4*)(W + (long)(bn * 128 + row) * K_DIM + kt + k4);
      ushort4 wb;
      wb.x = f2bf(rintf(fminf(fmaxf(wv.x / sc, -1.f), 1.f)));
      wb.y = f2bf(rintf(fminf(fmaxf(wv.y / sc, -1.f), 1.f)));
      wb.z = f2bf(rintf(fminf(fmaxf(wv.z / sc, -1.f), 1.f)));
      wb.w = f2bf(rintf(fminf(fmaxf(wv.w / sc, -1.f), 1.f)));
      *(ushort4*)(Bs + e) = wb;
    }
    __syncthreads();

    short8 a[4], b[4];
#pragma unroll
    for (int m = 0; m < 4; ++m)
      a[m] = *(const short8*)(AsB + aoff + m * (16 * 64));
#pragma unroll
    for (int n = 0; n < 4; ++n)
      b[n] = *(const short8*)(BsB + boff + n * (16 * 64));
#pragma unroll
    for (int m = 0; m < 4; ++m)
#pragma unroll
      for (int n = 0; n < 4; ++n)
        acc[m][n] = __builtin_amdgcn_mfma_f32_16x16x32_bf16(a[m], b[n], acc[m][n], 0, 0, 0);

    __syncthreads();
  }

  const long crow0 = (long)(bm * 128 + wr + fq * 4);
  const int ccol0 = bn * 128 + wc + fr;
#pragma unroll
  for (int m = 0; m < 4; ++m)
#pragma unroll
    for (int n = 0; n < 4; ++n)
#pragma unroll
      for (int j = 0; j < 4; ++j) {
        long row = crow0 + (long)(m * 16 + j);
        int col = ccol0 + n * 16;
        C[row * N_DIM + col] = acc[m][n][j] * sc;
      }
}

// ---------------- launch ----------------

extern "C" void kernel_launch(void* const* d_in, const int* in_sizes, int n_in,
                              void* d_out, int out_size, void* d_ws, size_t ws_size,
                              hipStream_t stream) {
  const float* x = (const float*)d_in[0];
  const float* w = (const float*)d_in[1];
  float* out = (float*)d_out;

  char* ws = (char*)d_ws;
  double* partials = (double*)ws;                 // 16 KB
  float* sp = (float*)(ws + 16384);               // scale (mean|W|)
  const size_t SROW_OFF = 32768;                  // 8192 floats = 32 KB
  const size_t WQ_OFF = SROW_OFF + 32768;
  const size_t XQ_OFF = WQ_OFF + (size_t)NELEM_W; // i8
  const size_t NEEDED = XQ_OFF + (size_t)NELEM_X; // ~96 MB

  reduce_absw<<<2048, 256, 0, stream>>>((const float4*)w, partials, (int)(NELEM_W / 4));
  finalize_scale<<<1, 256, 0, stream>>>(partials, sp);

  if (ws_size >= NEEDED) {
    float* s_row = (float*)(ws + SROW_OFF);
    char* wq = ws + WQ_OFF;
    char* xq = ws + XQ_OFF;
    quant_w_i8<<<2048, 256, 0, stream>>>((const float4*)w, wq, sp, (int)(NELEM_W / 4));
    quant_x_i8<<<M_DIM, 256, 0, stream>>>(x, xq, s_row);

    static const int lds_bytes = 49152;
    (void)hipFuncSetAttribute((const void*)gemm_i8,
                              hipFuncAttributeMaxDynamicSharedMemorySize, lds_bytes);
    const int grid = (M_DIM / 128) * (N_DIM / 256); // 64 * 64 = 4096
    gemm_i8<<<grid, 512, lds_bytes, stream>>>(xq, wq, out, sp, s_row);
  } else {
    const int grid = (M_DIM / 128) * (N_DIM / 128);
    gemm_fly<<<grid, 256, 0, stream>>>(x, w, out, sp);
  }
}